// Round 2
// 271.214 us; speedup vs baseline: 1.0009x; 1.0009x over previous
//
#include <hip/hip_runtime.h>
#include <math.h>

#define Bsz 64
#define Nn  256
#define Hh  1024
#define NK  768

typedef __bf16 bf16;
typedef bf16 bf16x4 __attribute__((ext_vector_type(4)));
typedef bf16 bf16x8 __attribute__((ext_vector_type(8)));
typedef float floatx4 __attribute__((ext_vector_type(4)));

#define KT_ROWS   1026          // kTp rows per batch: h = -1 .. 1024
#define KT_BSTRIDE (KT_ROWS * 256)   // 262656 elements per batch

__device__ __forceinline__ void gl_lds16(const bf16* g, bf16* l) {
    __builtin_amdgcn_global_load_lds(
        (__attribute__((address_space(1))) void*)(g),
        (__attribute__((address_space(3))) void*)(l), 16, 0, 0);
}

// ---------------------------------------------------------------------------
// Prep v2:
//   blocks 0..2047    : kin[b][i][h] fp32 -> kTp[b][h+1][i] bf16 transpose,
//                       tile 64 i x 128 h, row-permuted LDS (4-way max conflict)
//   blocks 2048..4095 : grid-stride cast f->bf16 then W_lin->bf16,
//                       32B loads / 16B stores per thread-iteration
// ---------------------------------------------------------------------------
__global__ __launch_bounds__(256) void prep_kernel(
    const float* __restrict__ f, const float* __restrict__ wl,
    const float* __restrict__ kin,
    bf16* __restrict__ fbf, bf16* __restrict__ wlbf, bf16* __restrict__ kTp)
{
    __shared__ bf16 T[128 * 72];
    const int tid = threadIdx.x;
    const int bid = blockIdx.x;

    if (bid >= 2048) {
        // ---- grid-stride cast path ----
        const int NF8 = 2097152;         // 64*256*1024 / 8
        const int NW8 = 98304;           // 768*1024 / 8
        const int STR = 524288;          // 2048 blocks * 256 threads
        for (int u = (bid - 2048) * 256 + tid; u < NF8 + NW8; u += STR) {
            const float4* s4; bf16* dst; int idx;
            if (u < NF8) { idx = u;        s4 = (const float4*)f  + (size_t)u * 2;   dst = fbf; }
            else         { idx = u - NF8;  s4 = (const float4*)wl + (size_t)idx * 2; dst = wlbf; }
            float4 a = s4[0];
            float4 c = s4[1];
            bf16x8 o = {(bf16)a.x, (bf16)a.y, (bf16)a.z, (bf16)a.w,
                        (bf16)c.x, (bf16)c.y, (bf16)c.z, (bf16)c.w};
            ((bf16x8*)dst)[idx] = o;
        }
        return;
    }

    // ---- kT transpose path: block = (b, ib, hb), tile i0+0..63 x h0+0..127 ----
    const int hb = bid & 7, ib = (bid >> 3) & 3, b = bid >> 5;
    const int i0 = ib * 64, h0 = hb * 128;
    const float* src = kin + ((size_t)b << 18);
    bf16* dstb = kTp + (size_t)b * KT_BSTRIDE;

    if (hb == 0 && ib == 0) {
        dstb[tid] = (bf16)0.f;                       // h = -1 row
        dstb[(size_t)1025 * 256 + tid] = (bf16)0.f;  // h = 1024 row
    }
    // Read 64i x 128h fp32; store into LDS with physical row = ((row&3)<<5)|(row>>2)
    // so each of the 4 unrolled writes lands at word-stride 36 (bank 4*c8): 4-way max.
    #pragma unroll
    for (int j = 0; j < 8; ++j) {
        int s  = tid + j * 256;          // 0..2047
        int il = s >> 5;                 // i-local 0..63
        int c8 = s & 31;                 // h-quad  0..31
        float4 v = *(const float4*)&src[(size_t)(i0 + il) * Hh + h0 + c8 * 4];
        T[(c8      ) * 72 + il] = (bf16)v.x;   // logical row c8*4+0
        T[(32 + c8 ) * 72 + il] = (bf16)v.y;   // logical row c8*4+1
        T[(64 + c8 ) * 72 + il] = (bf16)v.z;   // logical row c8*4+2
        T[(96 + c8 ) * 72 + il] = (bf16)v.w;   // logical row c8*4+3
    }
    __syncthreads();
    #pragma unroll
    for (int p = 0; p < 4; ++p) {
        int hl = (tid >> 3) + p * 32;    // h-local 0..127
        int q  = tid & 7;
        int pr = ((hl & 3) << 5) | (hl >> 2);   // physical LDS row
        bf16x8 v = *(const bf16x8*)&T[pr * 72 + q * 8];
        *(bf16x8*)&dstb[(size_t)(h0 + hl + 1) * 256 + i0 + q * 8] = v;
    }
}

// ---------------------------------------------------------------------------
// Stage 1: C[row=(b,n)][col=o'] = f_bf[row,:] . W_lin[o',:]  (K=1024)
// 128x192 tile (192 = 3 taps x 64 i), BK=64, 4 waves (2m x 2n of 64x96).
// Staging via gl_lds16. Epilogue via LDS (pitch 200): +bias, unscramble to
// wgt3[b][t][n][i], coalesced 16B stores.   (unchanged)
// ---------------------------------------------------------------------------
__global__ __launch_bounds__(256) void gemm1_mfma(
    const bf16* __restrict__ A,    // [16384][1024]
    const bf16* __restrict__ Bw,   // [768][1024]
    const float* __restrict__ bias,
    bf16* __restrict__ wgt3)       // [64*3][256][256]
{
    __shared__ bf16 smem[25600];   // staging As[2][4096]|Bs[2][6144]; epi Cs[128][200]
    bf16* As = smem;
    bf16* Bs = smem + 8192;
    const int tid  = threadIdx.x;
    const int wave = tid >> 6, lane = tid & 63;
    const int row0 = blockIdx.y * 128;
    const int col0 = blockIdx.x * 192;

    const bf16* gA[4]; bf16* lA[4];
    #pragma unroll
    for (int j = 0; j < 4; ++j) {
        int s = tid + j * 256;               // 0..1023
        int reg = s >> 9, rem = s & 511, row = rem >> 2, quad = rem & 3;
        gA[j] = A + (size_t)(row0 + row) * Hh + reg * 32 + quad * 8;
        lA[j] = As + s * 8;
    }
    const bf16* gB[6]; bf16* lB[6];
    #pragma unroll
    for (int j = 0; j < 6; ++j) {
        int s = tid + j * 256;               // 0..1535
        int reg = s / 768, rem = s - reg * 768, row = rem >> 2, quad = rem & 3;
        gB[j] = Bw + (size_t)(col0 + row) * Hh + reg * 32 + quad * 8;
        lB[j] = Bs + s * 8;
    }

    const int wm = wave & 1, wn = wave >> 1;
    const int fm = lane & 15, koct = (lane >> 4) * 8;

    floatx4 zero = {0.f, 0.f, 0.f, 0.f};
    floatx4 acc[4][6];
    #pragma unroll
    for (int i = 0; i < 4; ++i)
        #pragma unroll
        for (int j = 0; j < 6; ++j) acc[i][j] = zero;

    for (int k0 = 0; k0 < Hh; k0 += 64) {
        #pragma unroll
        for (int j = 0; j < 4; ++j) gl_lds16(gA[j] + k0, lA[j]);
        #pragma unroll
        for (int j = 0; j < 6; ++j) gl_lds16(gB[j] + k0, lB[j]);
        __syncthreads();
        #pragma unroll
        for (int q = 0; q < 2; ++q) {
            bf16x8 af[4], bfr[6];
            #pragma unroll
            for (int mt = 0; mt < 4; ++mt)
                af[mt] = *(const bf16x8*)&As[q * 4096 + (wm * 64 + mt * 16 + fm) * 32 + koct];
            #pragma unroll
            for (int nt = 0; nt < 6; ++nt)
                bfr[nt] = *(const bf16x8*)&Bs[q * 6144 + (wn * 96 + nt * 16 + fm) * 32 + koct];
            #pragma unroll
            for (int mt = 0; mt < 4; ++mt)
                #pragma unroll
                for (int nt = 0; nt < 6; ++nt)
                    acc[mt][nt] = __builtin_amdgcn_mfma_f32_16x16x32_bf16(
                        af[mt], bfr[nt], acc[mt][nt], 0, 0, 0);
        }
        __syncthreads();
    }

    // Epilogue: acc -> Cs[128][192] (pitch 200), then coalesced unscramble.
    const int b  = row0 >> 8;
    const int nb = row0 & 255;
    bf16* Cs = smem;
    #pragma unroll
    for (int nt = 0; nt < 6; ++nt) {
        int c = wn * 96 + nt * 16 + fm;
        float bl = bias[col0 + c];
        #pragma unroll
        for (int mt = 0; mt < 4; ++mt) {
            int rb = wm * 64 + mt * 16 + (lane >> 4) * 4;
            #pragma unroll
            for (int r = 0; r < 4; ++r)
                Cs[(rb + r) * 200 + c] = (bf16)(acc[mt][nt][r] + bl);
        }
    }
    __syncthreads();
    const int i0 = blockIdx.x * 64;
    #pragma unroll
    for (int j = 0; j < 12; ++j) {
        int s = tid + j * 256;               // 0..3071
        int t = s >> 10, rem = s & 1023, n = rem >> 3, q8 = rem & 7;
        bf16x8 v;
        #pragma unroll
        for (int u = 0; u < 8; ++u)
            v[u] = Cs[n * 200 + (q8 * 8 + u) * 3 + t];
        *(bf16x8*)&wgt3[((size_t)(b * 3 + t) << 16) + ((size_t)(nb + n) << 8) + i0 + q8 * 8] = v;
    }
}

// ---------------------------------------------------------------------------
// Stage 2: cbuf[b][o][h] = sum_{t,i} wgt3[b][t][o][i] * kTp[b][h+t][i]  (bf16)
// Block = (b, 64-o, 256-h) -> grid 4096. 8 i-chunks of 32; gl_lds16 staging.
// (unchanged)
// ---------------------------------------------------------------------------
__global__ __launch_bounds__(256, 3) void conv_mfma(
    const bf16* __restrict__ kTp,   // [64][1026][256]
    const bf16* __restrict__ wgt3,  // [64*3][256][256]
    bf16* __restrict__ cbuf)        // [64][256][1024] bf16
{
    __shared__ bf16 As[6144];       // [t][o(64)][i(32)]  12 KB
    __shared__ bf16 Ks[8256];       // [row(258)][i(32)]  16.5 KB
    const int tid  = threadIdx.x;
    const int wave = tid >> 6, lane = tid & 63;
    const int b  = blockIdx.z;
    const int o0 = blockIdx.y * 64;
    const int h0 = blockIdx.x * 256;
    const int wm = wave & 1, wn = wave >> 1;
    const int fm = lane & 15, koct = (lane >> 4) * 8;

    const bf16* gA[3]; bf16* lA[3];
    #pragma unroll
    for (int j = 0; j < 3; ++j) {
        int s = tid + j * 256;               // 0..767
        int t = s >> 8, rem = s & 255, o = rem >> 2, iq = rem & 3;
        gA[j] = wgt3 + ((size_t)(b * 3 + t) << 16) + ((size_t)(o0 + o) << 8) + iq * 8;
        lA[j] = As + s * 8;
    }
    const bf16* kb = kTp + (size_t)b * KT_BSTRIDE;
    const bf16* gK[4]; bf16* lK[4];
    #pragma unroll
    for (int j = 0; j < 4; ++j) {
        int s = tid + j * 256;               // 0..1023 -> rows 0..255
        int r = s >> 2, quad = s & 3;
        gK[j] = kb + (size_t)(h0 + r) * 256 + quad * 8;
        lK[j] = Ks + s * 8;
    }

    floatx4 zero = {0.f, 0.f, 0.f, 0.f};
    floatx4 acc[2][8];
    #pragma unroll
    for (int i = 0; i < 2; ++i)
        #pragma unroll
        for (int j = 0; j < 8; ++j) acc[i][j] = zero;

    for (int ic = 0; ic < 8; ++ic) {
        const int i0 = ic * 32;
        __syncthreads();
        #pragma unroll
        for (int j = 0; j < 3; ++j) gl_lds16(gA[j] + i0, lA[j]);
        #pragma unroll
        for (int j = 0; j < 4; ++j) gl_lds16(gK[j] + i0, lK[j]);
        if (tid < 8) {                       // halo rows 256..257
            int r = 256 + (tid >> 2), q = tid & 3;
            bf16x8 v = *(const bf16x8*)&kb[(size_t)(h0 + r) * 256 + i0 + q * 8];
            *(bf16x8*)&Ks[r * 32 + q * 8] = v;
        }
        __syncthreads();
        #pragma unroll
        for (int t = 0; t < 3; ++t) {
            bf16x8 af[2], bfr[8];
            #pragma unroll
            for (int mt = 0; mt < 2; ++mt)
                af[mt] = *(const bf16x8*)&As[t * 2048 + (wm * 32 + mt * 16 + fm) * 32 + koct];
            #pragma unroll
            for (int nt = 0; nt < 8; ++nt)
                bfr[nt] = *(const bf16x8*)&Ks[(wn * 128 + nt * 16 + fm + t) * 32 + koct];
            #pragma unroll
            for (int mt = 0; mt < 2; ++mt)
                #pragma unroll
                for (int nt = 0; nt < 8; ++nt)
                    acc[mt][nt] = __builtin_amdgcn_mfma_f32_16x16x32_bf16(
                        af[mt], bfr[nt], acc[mt][nt], 0, 0, 0);
        }
    }

    #pragma unroll
    for (int mt = 0; mt < 2; ++mt) {
        int o = o0 + wm * 32 + mt * 16 + (lane >> 4) * 4;
        #pragma unroll
        for (int nt = 0; nt < 8; ++nt) {
            int h = h0 + wn * 128 + nt * 16 + fm;
            #pragma unroll
            for (int r = 0; r < 4; ++r)
                cbuf[((size_t)(b * 256 + o + r) << 10) + h] = (bf16)acc[mt][nt][r];
        }
    }
}

// ---------------------------------------------------------------------------
// Stage 3 v2: LayerNorm, 2048 blocks x 8 rows. Two rows per iteration
// (half-block each, 16B loads), gamma/beta hoisted, parity-double-buffered
// LDS partials -> one __syncthreads per row-pair.
// ---------------------------------------------------------------------------
__global__ __launch_bounds__(256) void ln_kernel(
    const bf16* __restrict__ cbuf, const float* __restrict__ gamma,
    const float* __restrict__ beta, float* __restrict__ out)
{
    const int tid  = threadIdx.x;
    const int t    = tid & 127;      // position within row (x8 elems)
    const int half = tid >> 7;       // which row of the pair
    float4 g0  = ((const float4*)gamma)[t * 2];
    float4 g1  = ((const float4*)gamma)[t * 2 + 1];
    float4 be0 = ((const float4*)beta)[t * 2];
    float4 be1 = ((const float4*)beta)[t * 2 + 1];
    __shared__ float r1[2][4], r2[2][4];
    #pragma unroll
    for (int it = 0; it < 4; ++it) {
        const int row = (blockIdx.x << 3) + it * 2 + half;
        bf16x8 v = *(const bf16x8*)(cbuf + ((size_t)row << 10) + t * 8);
        float x[8];
        float s1 = 0.f, s2 = 0.f;
        #pragma unroll
        for (int u = 0; u < 8; ++u) {
            x[u] = (float)v[u];
            s1 += x[u];
            s2 += x[u] * x[u];
        }
        #pragma unroll
        for (int m = 1; m < 64; m <<= 1) {
            s1 += __shfl_xor(s1, m, 64);
            s2 += __shfl_xor(s2, m, 64);
        }
        const int p = it & 1;
        if ((tid & 63) == 0) { r1[p][tid >> 6] = s1; r2[p][tid >> 6] = s2; }
        __syncthreads();
        float S1 = r1[p][2 * half] + r1[p][2 * half + 1];
        float S2 = r2[p][2 * half] + r2[p][2 * half + 1];
        float mu   = S1 * (1.0f / 1024.0f);
        float var  = S2 * (1.0f / 1024.0f) - mu * mu;
        float rstd = rsqrtf(var + 1e-5f);
        float4 o0, o1;
        o0.x = (x[0] - mu) * rstd * g0.x + be0.x;
        o0.y = (x[1] - mu) * rstd * g0.y + be0.y;
        o0.z = (x[2] - mu) * rstd * g0.z + be0.z;
        o0.w = (x[3] - mu) * rstd * g0.w + be0.w;
        o1.x = (x[4] - mu) * rstd * g1.x + be1.x;
        o1.y = (x[5] - mu) * rstd * g1.y + be1.y;
        o1.z = (x[6] - mu) * rstd * g1.z + be1.z;
        o1.w = (x[7] - mu) * rstd * g1.w + be1.w;
        float* orow = out + ((size_t)row << 10) + t * 8;
        ((float4*)orow)[0] = o0;
        ((float4*)orow)[1] = o1;
    }
}

extern "C" void kernel_launch(void* const* d_in, const int* in_sizes, int n_in,
                              void* d_out, int out_size, void* d_ws, size_t ws_size,
                              hipStream_t stream) {
    const float* f     = (const float*)d_in[0];
    const float* kin   = (const float*)d_in[1];
    const float* W_lin = (const float*)d_in[2];
    const float* b_lin = (const float*)d_in[3];
    const float* gamma = (const float*)d_in[4];
    const float* beta  = (const float*)d_in[5];
    float* out = (float*)d_out;

    char* ws = (char*)d_ws;
    bf16* fbf  = (bf16*)(ws);                   // 33.55 MB (dead after gemm1)
    bf16* cbuf = (bf16*)(ws);                   // 33.55 MB, aliases fbf
    bf16* wlbf = (bf16*)(ws + 33554432);        // 1.57 MB
    bf16* kTp  = (bf16*)(ws + 35127296);        // 33.62 MB
    bf16* wgt3 = (bf16*)(ws + 68747264);        // 25.17 MB -> total ~93.9 MB

    prep_kernel<<<4096, 256, 0, stream>>>(f, W_lin, kin, fbf, wlbf, kTp);
    gemm1_mfma<<<dim3(4, 128), 256, 0, stream>>>(fbf, wlbf, b_lin, wgt3);
    conv_mfma<<<dim3(4, 4, 64), 256, 0, stream>>>(kTp, wgt3, cbuf);
    ln_kernel<<<2048, 256, 0, stream>>>(cbuf, gamma, beta, out);
}